// Round 17
// baseline (32.098 us; speedup 1.0000x reference)
//
#include <hip/hip_runtime.h>
#include <math.h>

#define NWIN   400
#define NSHIFT 160
#define NMELS  80
#define NFRM   998
#define WLEN   160000
#define FPB    12
#define BPB    84           // frame-blocks per batch (83 full + 1 tail of 2)
#define EPSV   1.1920929e-07f

// ================= compile-time table generation (no setup kernel) ==========
constexpr double KPI = 3.14159265358979323846;

constexpr double kcos(double x) {           // |x| <= 7, err < 1e-14
    double x2 = x * x, t = 1.0, s = 1.0;
    for (int k = 1; k <= 22; ++k) { t *= -x2 / (double)((2*k-1)*(2*k)); s += t; }
    return s;
}
constexpr double ksin(double x) {
    double x2 = x * x, t = x, s = x;
    for (int k = 1; k <= 22; ++k) { t *= -x2 / (double)((2*k)*(2*k+1)); s += t; }
    return s;
}
constexpr double kln(double a) {            // a > 0
    double m = a; int e = 0;
    while (m < 0.70710678118654752) { m *= 2.0; --e; }
    while (m >= 1.41421356237309505) { m *= 0.5; ++e; }
    double z = (m - 1.0) / (m + 1.0), z2 = z * z, t = z, s = 0.0;
    for (int k = 0; k <= 14; ++k) { s += t / (double)(2*k+1); t *= z2; }
    return 2.0 * s + (double)e * 0.69314718055994530942;
}
constexpr double kexp(double y) {           // |y| <= 10
    int n = (int)(y * 1.4426950408889634 + (y >= 0.0 ? 0.5 : -0.5));
    double r = y - (double)n * 0.69314718055994530942;
    double t = 1.0, s = 1.0;
    for (int k = 1; k <= 16; ++k) { t *= r / (double)k; s += t; }
    double p = 1.0;
    int an = n >= 0 ? n : -n;
    for (int i = 0; i < an; ++i) p *= (n >= 0 ? 2.0 : 0.5);
    return s * p;
}

struct alignas(16) WinT  { float v[NWIN]; };
struct alignas(16) Tw16T { float v[3][64][2]; };
struct alignas(16) TwaT  { float v[4][64][2]; };
struct alignas(16) WexpT { float v[128][2]; };
struct alignas(16) MelT  { int base[NMELS]; int nc[NMELS]; float w[3][NMELS][8]; };

constexpr WinT make_win() {
    WinT t{};
    for (int n = 0; n < NWIN; ++n) {
        double a = 0.5 - 0.5 * kcos(2.0 * KPI * (double)n / 399.0);
        if (a < 0.0) a = 0.0;
        t.v[n] = (a <= 0.0) ? 0.0f : (float)kexp(0.85 * kln(a));  // a^0.85
    }
    return t;
}
constexpr Tw16T make_tw16() {
    Tw16T t{};
    for (int c = 1; c <= 3; ++c)
        for (int L = 0; L < 64; ++L) {
            int a = L & 3;
            double th = -KPI * (double)(a * c) / 8.0;
            t.v[c-1][L][0] = (float)kcos(th);
            t.v[c-1][L][1] = (float)ksin(th);
        }
    return t;
}
constexpr TwaT make_twa() {
    TwaT t{};
    for (int c = 0; c < 4; ++c)
        for (int L = 0; L < 64; ++L) {
            int q = L >> 2, a = L & 3;
            int r2 = ((a & 1) << 1) | (a >> 1);
            double th = -KPI * (double)(q * (c + 4 * r2)) / 128.0;
            t.v[c][L][0] = (float)kcos(th);
            t.v[c][L][1] = (float)ksin(th);
        }
    return t;
}
constexpr WexpT make_wexp() {
    WexpT t{};
    for (int k = 0; k < 128; ++k) {
        double th = KPI * (double)k / 256.0;
        t.v[k][0] = (float)kcos(th);
        t.v[k][1] = (float)(-ksin(th));
    }
    return t;
}
constexpr MelT make_mel() {
    MelT t{};
    double ML = 1127.0 * kln(1.0 + 20.0 / 700.0);
    double MH = 1127.0 * kln(1.0 + 8000.0 / 700.0);
    double DD = (MH - ML) / 81.0;
    for (int j = 0; j < NMELS; ++j) {
        double mlo = ML + (double)j * DD;
        double mhi = mlo + 2.0 * DD;
        double flo = 700.0 * (kexp(mlo / 1127.0) - 1.0);
        double fhi = 700.0 * (kexp(mhi / 1127.0) - 1.0);
        int blo = (int)(flo / 31.25); if (blo < 1) blo = 1;
        int bhi = (int)(fhi / 31.25) + 1; if (bhi > 255) bhi = 255;
        int base = blo & ~7;                 // max span 17 bins -> <=3 chunks
        int nc = (bhi - base + 8) >> 3; if (nc > 3) nc = 3;
        t.base[j] = base;
        t.nc[j]   = nc;
        for (int c = 0; c < 3; ++c)
            for (int i = 0; i < 8; ++i) {
                int b = base + 8 * c + i;
                double w = 0.0;
                if (b >= 1 && b <= 255) {
                    double u = (1127.0 * kln(1.0 + (double)b * 31.25 / 700.0) - ML) / DD;
                    double lo = u - (double)j, hi = (double)(j + 2) - u;
                    w = lo < hi ? lo : hi;
                    if (w < 0.0) w = 0.0;    // triangle clamps outside [blo,bhi]
                }
                t.w[c][j][i] = (float)w;
            }
    }
    return t;
}

__device__ constexpr WinT  g_win  = make_win();
__device__ constexpr Tw16T g_tw16 = make_tw16();
__device__ constexpr TwaT  g_twa  = make_twa();
__device__ constexpr WexpT g_wexp = make_wexp();
__device__ constexpr MelT  g_mel  = make_mel();

// ============================================================================
// DPP cross-lane helpers (VALU pipe, no LDS, no address math)
#define DPPF(v, ctrl) __int_as_float(__builtin_amdgcn_mov_dpp(__float_as_int(v), ctrl, 0xF, 0xF, true))
// quad_perm xor2: [2,3,0,1] = 0x4E ; xor1: [1,0,3,2] = 0xB1
// row_shr:N = 0x110+N ; row_bcast15 = 0x142 ; row_bcast31 = 0x143

// full-wave sum via DPP (GCN canonical): total lands in lane 63, then
// broadcast via readlane. All VALU pipe - no LDS ops, short dep chain.
__device__ __forceinline__ float wave_sum(float v) {
    v += DPPF(v, 0x111);        // row_shr:1
    v += DPPF(v, 0x112);        // row_shr:2
    v += DPPF(v, 0x114);        // row_shr:4
    v += DPPF(v, 0x118);        // row_shr:8  -> lane 15 of each row = row sum
    v += DPPF(v, 0x142);        // row_bcast15
    v += DPPF(v, 0x143);        // row_bcast31 -> lane 63 = total
    return __int_as_float(__builtin_amdgcn_readlane(__float_as_int(v), 63));
}

// DFT-16: radix-4 over local slots (sub-idx b), W16^{ac} twiddle, radix-4
// across the quad (sub-idx a) via DPP. Input: slot b holds x[a+4b] (a=lane&3).
// Output: slot c holds Y[c + 4*rev2(a)].
__device__ __forceinline__ void dft16_quad(float zx[4], float zy[4],
    float2 w1, float2 w2, float2 w3, bool b1, bool b2, bool b3)
{
    float t0x = zx[0]+zx[2], t0y = zy[0]+zy[2];
    float t1x = zx[1]+zx[3], t1y = zy[1]+zy[3];
    float t2x = zx[0]-zx[2], t2y = zy[0]-zy[2];
    float t3x = zx[1]-zx[3], t3y = zy[1]-zy[3];
    float p0x = t0x+t1x, p0y = t0y+t1y;
    float p2x = t0x-t1x, p2y = t0y-t1y;
    float p1x = t2x+t3y, p1y = t2y-t3x;          // W4 = -i
    float p3x = t2x-t3y, p3y = t2y+t3x;
    zx[0] = p0x;                     zy[0] = p0y;
    zx[1] = p1x*w1.x - p1y*w1.y;     zy[1] = p1x*w1.y + p1y*w1.x;
    zx[2] = p2x*w2.x - p2y*w2.y;     zy[2] = p2x*w2.y + p2y*w2.x;
    zx[3] = p3x*w3.x - p3y*w3.y;     zy[3] = p3x*w3.y + p3y*w3.x;
    #pragma unroll
    for (int c = 0; c < 4; ++c) {
        float vx = zx[c], vy = zy[c];
        float ex = DPPF(vx, 0x4E), ey = DPPF(vy, 0x4E);   // partner a^2
        float ux = ex + (b2 ? -vx : vx);
        float uy = ey + (b2 ? -vy : vy);
        float rx = b3 ? uy : ux;                          // *(-i) on lane a==3
        float ry = b3 ? -ux : uy;
        float fx = DPPF(rx, 0xB1), fy = DPPF(ry, 0xB1);   // partner a^1
        zx[c] = fx + (b1 ? -rx : rx);
        zy[c] = fy + (b1 ? -ry : ry);
    }
}

// untangle pair power: X = E + W*O (and conj-partner), p = |X|^2
__device__ __forceinline__ void pairpow(float2 Zk, float2 Zm, float2 w,
                                        float& pk, float& pm)
{
    float Sx = Zk.x + Zm.x, Sy = Zk.y - Zm.y;   // 2E
    float Ox = Zk.y + Zm.y, Oy = Zm.x - Zk.x;   // 2O
    float Ux = fmaf(w.x, Ox, -w.y * Oy), Uy = fmaf(w.x, Oy, w.y * Ox);
    float q1 = Sx + Ux, q2 = Sy + Uy;
    float q3 = Sx - Ux, q4 = Sy - Uy;
    pk = 0.25f * fmaf(q1, q1, q2 * q2);
    pm = 0.25f * fmaf(q3, q3, q4 * q4);
}

__global__ __launch_bounds__(256, 5)
void fbank_kernel(const float* __restrict__ wav, float* __restrict__ out)
{
    __shared__ __align__(16) float zbf[FPB][512];   // y -> B -> X -> pw, in place
    __shared__ __align__(16) float res[FPB][NMELS]; // [slot][mel]: conflict-free
    // LDS = 24576 + 3840 = 28416 B -> 5 blocks/CU x 4 waves = 20 waves/CU

    const int tid  = threadIdx.x;
    const int lane = tid & 63;
    const int wv   = tid >> 6;
    const int bb   = blockIdx.x / BPB;
    const int f0   = (blockIdx.x % BPB) * FPB;
    // tail block (f0=996): clamp all three; clamped slots never emitted
    const int fA   = min(f0 + wv,     NFRM - 1);
    const int fB   = min(f0 + wv + 4, NFRM - 1);
    const int fC   = min(f0 + wv + 8, NFRM - 1);

    float* zfA = zbf[wv];
    float* zfB = zbf[wv + 4];
    float* zfC = zbf[wv + 8];

    // ---- window regs, shared by all frames ----
    float wn[7];
    #pragma unroll
    for (int t = 0; t < 7; ++t) {
        int n = 64 * t + lane;
        wn[t] = (t < 6 || lane < 16) ? g_win.v[n] : 0.0f;
    }

    // ---- preprocess 3 frames: coalesced loads, de-mean, pre-emph, window ----
    #pragma unroll
    for (int fi = 0; fi < 3; ++fi) {
        const int frame = fi == 0 ? fA : (fi == 1 ? fB : fC);
        float* zf = fi == 0 ? zfA : (fi == 1 ? zfB : zfC);
        const float* xp = wav + (size_t)bb * WLEN + (size_t)frame * NSHIFT;
        float xc[7], xm[7];
        float s = 0.0f;
        #pragma unroll
        for (int t = 0; t < 7; ++t) {
            int n = 64 * t + lane;
            bool vn = (t < 6 || lane < 16);
            xc[t] = vn ? xp[n] : 0.0f;
            xm[t] = (vn && n > 0) ? xp[n - 1] : 0.0f;   // L1-hit reload
            s += xc[t];
        }
        if (lane == 0) xm[0] = xc[0];                   // ref: prev[0] = x[0]
        const float mu3 = 0.03f * (wave_sum(s) * (1.0f / (float)NWIN));
        #pragma unroll
        for (int t = 0; t < 7; ++t) {
            bool vn = (t < 6 || lane < 16);
            float y = vn ? (fmaf(-0.97f, xm[t], xc[t]) - mu3) * wn[t] : 0.0f;
            zf[64 * t + lane] = y;                      // linear: 2-way, free
        }
        zf[448 + lane] = 0.0f;                          // pad y[448..511]
    }

    // ---- 256-pt FFT as radix-16 x radix-16, in place, 3 frames interleaved ----
    const int a  = lane & 3, q = lane >> 2;
    const int r2 = ((a & 1) << 1) | (a >> 1);           // rev2(a)
    const bool b1 = (a & 1) != 0, b2 = (a & 2) != 0, b3 = (a == 3);
    {
        const float2* t16 = (const float2*)g_tw16.v;
        float2 w1 = t16[lane], w2 = t16[64 + lane], w3 = t16[128 + lane];
        const float2* twa = (const float2*)g_twa.v;
        float2 ta[4];
        #pragma unroll
        for (int c = 0; c < 4; ++c) ta[c] = twa[c * 64 + lane];

        float2* zcA = (float2*)zfA;
        float2* zcB = (float2*)zfB;
        float2* zcC = (float2*)zfC;
        const int ra = q + 16 * a;
        float xA[4], yA[4], xB[4], yB[4], xC[4], yC[4];

        // pass A: read z linear (all reads precede in-place writes; DS ops
        // are in-order per wave)
        #pragma unroll
        for (int b = 0; b < 4; ++b) { float2 v = zcA[ra + 64*b]; xA[b] = v.x; yA[b] = v.y; }
        #pragma unroll
        for (int b = 0; b < 4; ++b) { float2 v = zcB[ra + 64*b]; xB[b] = v.x; yB[b] = v.y; }
        #pragma unroll
        for (int b = 0; b < 4; ++b) { float2 v = zcC[ra + 64*b]; xC[b] = v.x; yC[b] = v.y; }
        dft16_quad(xA, yA, w1, w2, w3, b1, b2, b3);
        dft16_quad(xB, yB, w1, w2, w3, b1, b2, b3);
        dft16_quad(xC, yC, w1, w2, w3, b1, b2, b3);
        #pragma unroll
        for (int c = 0; c < 4; ++c) {                   // twiddle + swz write
            int idx = 16*c + 64*r2 + q;
            int sw  = idx ^ ((idx >> 4) & 15);
            zcA[sw] = make_float2(xA[c]*ta[c].x - yA[c]*ta[c].y,
                                  xA[c]*ta[c].y + yA[c]*ta[c].x);
            zcB[sw] = make_float2(xB[c]*ta[c].x - yB[c]*ta[c].y,
                                  xB[c]*ta[c].y + yB[c]*ta[c].x);
            zcC[sw] = make_float2(xC[c]*ta[c].x - yC[c]*ta[c].y,
                                  xC[c]*ta[c].y + yC[c]*ta[c].x);
        }
        // pass B: read B[n1=a+4b][k1=q] swizzled
        #pragma unroll
        for (int b = 0; b < 4; ++b) {
            int idx = 16*q + a + 4*b;
            int sw  = idx ^ ((idx >> 4) & 15);
            float2 v = zcA[sw]; xA[b] = v.x; yA[b] = v.y;
            float2 u = zcB[sw]; xB[b] = u.x; yB[b] = u.y;
            float2 w = zcC[sw]; xC[b] = w.x; yC[b] = w.y;
        }
        dft16_quad(xA, yA, w1, w2, w3, b1, b2, b3);
        dft16_quad(xB, yB, w1, w2, w3, b1, b2, b3);
        dft16_quad(xC, yC, w1, w2, w3, b1, b2, b3);
        #pragma unroll
        for (int c = 0; c < 4; ++c) {                   // X natural order
            int idx = q + 16*c + 64*r2;
            zcA[idx] = make_float2(xA[c], yA[c]);
            zcB[idx] = make_float2(xB[c], yB[c]);
            zcC[idx] = make_float2(xC[c], yC[c]);
        }
    }

    // ---- single-phase untangle + power, in place, 3 frames ----
    {
        float2* zcA = (float2*)zfA;
        float2* zcB = (float2*)zfB;
        float2* zcC = (float2*)zfC;
        const float2* we = (const float2*)g_wexp.v;
        float2 wk1 = we[lane], wk2 = we[64 + lane];
        const int m1 = (256 - lane) & 255;              // 0 or 193..255
        const int m2 = 192 - lane;                      // 129..192
        // ALL reads first (per frame), then writes (in-order DS per wave).
        // Bin 0 has weight 0 in the mel table -> unconditional pw[m1] write.
        float pk, pm;
        {
            float2 k1v = zcA[lane], m1v = zcA[m1], k2v = zcA[64 + lane], m2v = zcA[m2];
            float2 c128 = zcA[128];
            pairpow(k1v, m1v, wk1, pk, pm); zfA[lane] = pk; zfA[m1] = pm;
            pairpow(k2v, m2v, wk2, pk, pm); zfA[64 + lane] = pk; zfA[m2] = pm;
            if (lane == 0) zfA[128] = fmaf(c128.x, c128.x, c128.y * c128.y);
        }
        {
            float2 k1v = zcB[lane], m1v = zcB[m1], k2v = zcB[64 + lane], m2v = zcB[m2];
            float2 c128 = zcB[128];
            pairpow(k1v, m1v, wk1, pk, pm); zfB[lane] = pk; zfB[m1] = pm;
            pairpow(k2v, m2v, wk2, pk, pm); zfB[64 + lane] = pk; zfB[m2] = pm;
            if (lane == 0) zfB[128] = fmaf(c128.x, c128.x, c128.y * c128.y);
        }
        {
            float2 k1v = zcC[lane], m1v = zcC[m1], k2v = zcC[64 + lane], m2v = zcC[m2];
            float2 c128 = zcC[128];
            pairpow(k1v, m1v, wk1, pk, pm); zfC[lane] = pk; zfC[m1] = pm;
            pairpow(k2v, m2v, wk2, pk, pm); zfC[64 + lane] = pk; zfC[m2] = pm;
            if (lane == 0) zfC[128] = fmaf(c128.x, c128.x, c128.y * c128.y);
        }
    }

    // ---- mel gather: tight windows (<=3 chunks, exec-masked), f32 weights ----
    {
        auto gather1 = [&](const float* pw, int j, int slot) {
            const int base = g_mel.base[j];
            const int nc   = g_mel.nc[j];
            float acc = 0.0f;
            #pragma unroll
            for (int c = 0; c < 3; ++c) {
                if (c == 0 || c < nc) {                 // masked lanes skip banks
                    float4 p0 = *(const float4*)&pw[base + 8 * c];
                    float4 p1 = *(const float4*)&pw[base + 8 * c + 4];
                    float4 wa = *(const float4*)&g_mel.w[c][j][0];
                    float4 wb = *(const float4*)&g_mel.w[c][j][4];
                    acc = fmaf(wa.x, p0.x, acc); acc = fmaf(wa.y, p0.y, acc);
                    acc = fmaf(wa.z, p0.z, acc); acc = fmaf(wa.w, p0.w, acc);
                    acc = fmaf(wb.x, p1.x, acc); acc = fmaf(wb.y, p1.y, acc);
                    acc = fmaf(wb.z, p1.z, acc); acc = fmaf(wb.w, p1.w, acc);
                }
            }
            res[slot][j] = __logf(fmaxf(acc, EPSV));    // linear in j: free
        };
        gather1(zfA, lane, wv);                         // mels 0..63, frame A
        gather1(zfB, lane, wv + 4);                     // mels 0..63, frame B
        gather1(zfC, lane, wv + 8);                     // mels 0..63, frame C
        if (lane < 48) {                                // mels 64..79, 3 frames
            int l2 = lane & 15, f = lane >> 4;          // f = 0,1,2
            const float* pw = f == 0 ? zfA : (f == 1 ? zfB : zfC);
            gather1(pw, 64 + l2, wv + 4 * f);
        }
    }
    __syncthreads();

    // ---- transposed output, 8B bursts (res reads linear in tid: free) ----
    const int nval = min(FPB, NFRM - f0);               // 12, or 2 in tail
    if (tid < NMELS) {
        size_t o = ((size_t)bb * NMELS + tid) * NFRM + (size_t)f0;
        *(float2*)&out[o] = make_float2(res[0][tid], res[1][tid]);
        if (nval == FPB) {
            *(float2*)&out[o + 2]  = make_float2(res[2][tid],  res[3][tid]);
            *(float2*)&out[o + 4]  = make_float2(res[4][tid],  res[5][tid]);
            *(float2*)&out[o + 6]  = make_float2(res[6][tid],  res[7][tid]);
            *(float2*)&out[o + 8]  = make_float2(res[8][tid],  res[9][tid]);
            *(float2*)&out[o + 10] = make_float2(res[10][tid], res[11][tid]);
        }
    }
}

extern "C" void kernel_launch(void* const* d_in, const int* in_sizes, int n_in,
                              void* d_out, int out_size, void* d_ws, size_t ws_size,
                              hipStream_t stream)
{
    const float* wav = (const float*)d_in[0];
    float* out = (float*)d_out;
    fbank_kernel<<<dim3(32 * BPB), dim3(256), 0, stream>>>(wav, out);
}

// Round 18
// 31.230 us; speedup vs baseline: 1.0278x; 1.0278x over previous
//
#include <hip/hip_runtime.h>
#include <math.h>

#define NWIN   400
#define NSHIFT 160
#define NMELS  80
#define NFRM   998
#define WLEN   160000
#define FPB    8
#define BPB    125          // frame-blocks per batch (124 full + 1 tail of 6)
#define EPSV   1.1920929e-07f

// ================= compile-time table generation (no setup kernel) ==========
constexpr double KPI = 3.14159265358979323846;

constexpr double kcos(double x) {           // |x| <= 7, err < 1e-14
    double x2 = x * x, t = 1.0, s = 1.0;
    for (int k = 1; k <= 22; ++k) { t *= -x2 / (double)((2*k-1)*(2*k)); s += t; }
    return s;
}
constexpr double ksin(double x) {
    double x2 = x * x, t = x, s = x;
    for (int k = 1; k <= 22; ++k) { t *= -x2 / (double)((2*k)*(2*k+1)); s += t; }
    return s;
}
constexpr double kln(double a) {            // a > 0
    double m = a; int e = 0;
    while (m < 0.70710678118654752) { m *= 2.0; --e; }
    while (m >= 1.41421356237309505) { m *= 0.5; ++e; }
    double z = (m - 1.0) / (m + 1.0), z2 = z * z, t = z, s = 0.0;
    for (int k = 0; k <= 14; ++k) { s += t / (double)(2*k+1); t *= z2; }
    return 2.0 * s + (double)e * 0.69314718055994530942;
}
constexpr double kexp(double y) {           // |y| <= 10
    int n = (int)(y * 1.4426950408889634 + (y >= 0.0 ? 0.5 : -0.5));
    double r = y - (double)n * 0.69314718055994530942;
    double t = 1.0, s = 1.0;
    for (int k = 1; k <= 16; ++k) { t *= r / (double)k; s += t; }
    double p = 1.0;
    int an = n >= 0 ? n : -n;
    for (int i = 0; i < an; ++i) p *= (n >= 0 ? 2.0 : 0.5);
    return s * p;
}

struct alignas(16) WinT  { float v[NWIN]; };
struct alignas(16) Tw16T { float v[3][64][2]; };
struct alignas(16) TwaT  { float v[4][64][2]; };
struct alignas(16) WexpT { float v[128][2]; };
struct alignas(16) MelT  { int base[NMELS]; int nc[NMELS]; float w[3][NMELS][8]; };

constexpr WinT make_win() {
    WinT t{};
    for (int n = 0; n < NWIN; ++n) {
        double a = 0.5 - 0.5 * kcos(2.0 * KPI * (double)n / 399.0);
        if (a < 0.0) a = 0.0;
        t.v[n] = (a <= 0.0) ? 0.0f : (float)kexp(0.85 * kln(a));  // a^0.85
    }
    return t;
}
constexpr Tw16T make_tw16() {
    Tw16T t{};
    for (int c = 1; c <= 3; ++c)
        for (int L = 0; L < 64; ++L) {
            int a = L & 3;
            double th = -KPI * (double)(a * c) / 8.0;
            t.v[c-1][L][0] = (float)kcos(th);
            t.v[c-1][L][1] = (float)ksin(th);
        }
    return t;
}
constexpr TwaT make_twa() {
    TwaT t{};
    for (int c = 0; c < 4; ++c)
        for (int L = 0; L < 64; ++L) {
            int q = L >> 2, a = L & 3;
            int r2 = ((a & 1) << 1) | (a >> 1);
            double th = -KPI * (double)(q * (c + 4 * r2)) / 128.0;
            t.v[c][L][0] = (float)kcos(th);
            t.v[c][L][1] = (float)ksin(th);
        }
    return t;
}
constexpr WexpT make_wexp() {
    WexpT t{};
    for (int k = 0; k < 128; ++k) {
        double th = KPI * (double)k / 256.0;
        t.v[k][0] = (float)kcos(th);
        t.v[k][1] = (float)(-ksin(th));
    }
    return t;
}
constexpr MelT make_mel() {
    MelT t{};
    double ML = 1127.0 * kln(1.0 + 20.0 / 700.0);
    double MH = 1127.0 * kln(1.0 + 8000.0 / 700.0);
    double DD = (MH - ML) / 81.0;
    for (int j = 0; j < NMELS; ++j) {
        double mlo = ML + (double)j * DD;
        double mhi = mlo + 2.0 * DD;
        double flo = 700.0 * (kexp(mlo / 1127.0) - 1.0);
        double fhi = 700.0 * (kexp(mhi / 1127.0) - 1.0);
        int blo = (int)(flo / 31.25); if (blo < 1) blo = 1;
        int bhi = (int)(fhi / 31.25) + 1; if (bhi > 255) bhi = 255;
        int base = blo & ~7;                 // max span 17 bins -> <=3 chunks
        int nc = (bhi - base + 8) >> 3; if (nc > 3) nc = 3;
        t.base[j] = base;
        t.nc[j]   = nc;
        for (int c = 0; c < 3; ++c)
            for (int i = 0; i < 8; ++i) {
                int b = base + 8 * c + i;
                double w = 0.0;
                if (b >= 1 && b <= 255) {
                    double u = (1127.0 * kln(1.0 + (double)b * 31.25 / 700.0) - ML) / DD;
                    double lo = u - (double)j, hi = (double)(j + 2) - u;
                    w = lo < hi ? lo : hi;
                    if (w < 0.0) w = 0.0;    // triangle clamps outside [blo,bhi]
                }
                t.w[c][j][i] = (float)w;
            }
    }
    return t;
}

__device__ constexpr WinT  g_win  = make_win();
__device__ constexpr Tw16T g_tw16 = make_tw16();
__device__ constexpr TwaT  g_twa  = make_twa();
__device__ constexpr WexpT g_wexp = make_wexp();
__device__ constexpr MelT  g_mel  = make_mel();

// ============================================================================
// DPP cross-lane helpers (VALU pipe, no LDS, no address math)
#define DPPF(v, ctrl) __int_as_float(__builtin_amdgcn_mov_dpp(__float_as_int(v), ctrl, 0xF, 0xF, true))
// quad_perm xor2: [2,3,0,1] = 0x4E ; xor1: [1,0,3,2] = 0xB1
// row_shr:N = 0x110+N ; row_bcast15 = 0x142 ; row_bcast31 = 0x143

// full-wave sum via DPP (GCN canonical): total lands in lane 63, then
// broadcast via readlane. All VALU pipe - no LDS ops, short dep chain.
__device__ __forceinline__ float wave_sum(float v) {
    v += DPPF(v, 0x111);        // row_shr:1
    v += DPPF(v, 0x112);        // row_shr:2
    v += DPPF(v, 0x114);        // row_shr:4
    v += DPPF(v, 0x118);        // row_shr:8  -> lane 15 of each row = row sum
    v += DPPF(v, 0x142);        // row_bcast15
    v += DPPF(v, 0x143);        // row_bcast31 -> lane 63 = total
    return __int_as_float(__builtin_amdgcn_readlane(__float_as_int(v), 63));
}

// DFT-16: radix-4 over local slots (sub-idx b), W16^{ac} twiddle, radix-4
// across the quad (sub-idx a) via DPP. Input: slot b holds x[a+4b] (a=lane&3).
// Output: slot c holds Y[c + 4*rev2(a)].
__device__ __forceinline__ void dft16_quad(float zx[4], float zy[4],
    float2 w1, float2 w2, float2 w3, bool b1, bool b2, bool b3)
{
    float t0x = zx[0]+zx[2], t0y = zy[0]+zy[2];
    float t1x = zx[1]+zx[3], t1y = zy[1]+zy[3];
    float t2x = zx[0]-zx[2], t2y = zy[0]-zy[2];
    float t3x = zx[1]-zx[3], t3y = zy[1]-zy[3];
    float p0x = t0x+t1x, p0y = t0y+t1y;
    float p2x = t0x-t1x, p2y = t0y-t1y;
    float p1x = t2x+t3y, p1y = t2y-t3x;          // W4 = -i
    float p3x = t2x-t3y, p3y = t2y+t3x;
    zx[0] = p0x;                     zy[0] = p0y;
    zx[1] = p1x*w1.x - p1y*w1.y;     zy[1] = p1x*w1.y + p1y*w1.x;
    zx[2] = p2x*w2.x - p2y*w2.y;     zy[2] = p2x*w2.y + p2y*w2.x;
    zx[3] = p3x*w3.x - p3y*w3.y;     zy[3] = p3x*w3.y + p3y*w3.x;
    #pragma unroll
    for (int c = 0; c < 4; ++c) {
        float vx = zx[c], vy = zy[c];
        float ex = DPPF(vx, 0x4E), ey = DPPF(vy, 0x4E);   // partner a^2
        float ux = ex + (b2 ? -vx : vx);
        float uy = ey + (b2 ? -vy : vy);
        float rx = b3 ? uy : ux;                          // *(-i) on lane a==3
        float ry = b3 ? -ux : uy;
        float fx = DPPF(rx, 0xB1), fy = DPPF(ry, 0xB1);   // partner a^1
        zx[c] = fx + (b1 ? -rx : rx);
        zy[c] = fy + (b1 ? -ry : ry);
    }
}

// untangle pair power: X = E + W*O (and conj-partner), p = |X|^2
__device__ __forceinline__ void pairpow(float2 Zk, float2 Zm, float2 w,
                                        float& pk, float& pm)
{
    float Sx = Zk.x + Zm.x, Sy = Zk.y - Zm.y;   // 2E
    float Ox = Zk.y + Zm.y, Oy = Zm.x - Zk.x;   // 2O
    float Ux = fmaf(w.x, Ox, -w.y * Oy), Uy = fmaf(w.x, Oy, w.y * Ox);
    float q1 = Sx + Ux, q2 = Sy + Uy;
    float q3 = Sx - Ux, q4 = Sy - Uy;
    pk = 0.25f * fmaf(q1, q1, q2 * q2);
    pm = 0.25f * fmaf(q3, q3, q4 * q4);
}

__global__ __launch_bounds__(256, 8)
void fbank_kernel(const float* __restrict__ wav, float* __restrict__ out)
{
    __shared__ __align__(16) float zbf[FPB][512];   // y -> B -> X -> pw, in place
    __shared__ __align__(16) float res[FPB][NMELS]; // [slot][mel]: conflict-free
    // LDS = 16384 + 2560 = 18944 B -> 8 blocks/CU (full 32-wave cap)

    const int tid  = threadIdx.x;
    const int lane = tid & 63;
    const int wv   = tid >> 6;
    const int bb   = blockIdx.x / BPB;
    const int f0   = (blockIdx.x % BPB) * FPB;
    const int fA   = f0 + wv;                       // <= 995, always valid
    const int fB   = min(f0 + wv + 4, NFRM - 1);    // clamp in tail block

    float* zfA = zbf[wv];
    float* zfB = zbf[wv + 4];

    // ---- window regs, shared by both frames ----
    float wn[7];
    #pragma unroll
    for (int t = 0; t < 7; ++t) {
        int n = 64 * t + lane;
        wn[t] = (t < 6 || lane < 16) ? g_win.v[n] : 0.0f;
    }

    // ---- preprocess both frames: coalesced loads, de-mean, pre-emph, window ----
    #pragma unroll
    for (int fi = 0; fi < 2; ++fi) {
        const int frame = fi ? fB : fA;
        float* zf = fi ? zfB : zfA;
        const float* xp = wav + (size_t)bb * WLEN + (size_t)frame * NSHIFT;
        float xc[7], xm[7];
        float s = 0.0f;
        #pragma unroll
        for (int t = 0; t < 7; ++t) {
            int n = 64 * t + lane;
            bool vn = (t < 6 || lane < 16);
            xc[t] = vn ? xp[n] : 0.0f;
            xm[t] = (vn && n > 0) ? xp[n - 1] : 0.0f;   // L1-hit reload
            s += xc[t];
        }
        if (lane == 0) xm[0] = xc[0];                   // ref: prev[0] = x[0]
        const float mu3 = 0.03f * (wave_sum(s) * (1.0f / (float)NWIN));
        #pragma unroll
        for (int t = 0; t < 7; ++t) {
            bool vn = (t < 6 || lane < 16);
            float y = vn ? (fmaf(-0.97f, xm[t], xc[t]) - mu3) * wn[t] : 0.0f;
            zf[64 * t + lane] = y;                      // linear: 2-way, free
        }
        zf[448 + lane] = 0.0f;                          // pad y[448..511]
    }

    // ---- 256-pt FFT as radix-16 x radix-16, in place, both frames ----
    const int a  = lane & 3, q = lane >> 2;
    const int r2 = ((a & 1) << 1) | (a >> 1);           // rev2(a)
    const bool b1 = (a & 1) != 0, b2 = (a & 2) != 0, b3 = (a == 3);
    {
        const float2* t16 = (const float2*)g_tw16.v;
        float2 w1 = t16[lane], w2 = t16[64 + lane], w3 = t16[128 + lane];
        const float2* twa = (const float2*)g_twa.v;
        float2 ta[4];
        #pragma unroll
        for (int c = 0; c < 4; ++c) ta[c] = twa[c * 64 + lane];

        float2* zcA = (float2*)zfA;
        float2* zcB = (float2*)zfB;
        const int ra = q + 16 * a;
        float xA[4], yA[4], xB[4], yB[4];

        // pass A: read z linear (all reads precede in-place writes; DS ops
        // are in-order per wave)
        #pragma unroll
        for (int b = 0; b < 4; ++b) { float2 v = zcA[ra + 64*b]; xA[b] = v.x; yA[b] = v.y; }
        #pragma unroll
        for (int b = 0; b < 4; ++b) { float2 v = zcB[ra + 64*b]; xB[b] = v.x; yB[b] = v.y; }
        dft16_quad(xA, yA, w1, w2, w3, b1, b2, b3);
        dft16_quad(xB, yB, w1, w2, w3, b1, b2, b3);
        #pragma unroll
        for (int c = 0; c < 4; ++c) {                   // twiddle + swz write
            int idx = 16*c + 64*r2 + q;
            int sw  = idx ^ ((idx >> 4) & 15);
            zcA[sw] = make_float2(xA[c]*ta[c].x - yA[c]*ta[c].y,
                                  xA[c]*ta[c].y + yA[c]*ta[c].x);
            zcB[sw] = make_float2(xB[c]*ta[c].x - yB[c]*ta[c].y,
                                  xB[c]*ta[c].y + yB[c]*ta[c].x);
        }
        // pass B: read B[n1=a+4b][k1=q] swizzled
        #pragma unroll
        for (int b = 0; b < 4; ++b) {
            int idx = 16*q + a + 4*b;
            int sw  = idx ^ ((idx >> 4) & 15);
            float2 v = zcA[sw]; xA[b] = v.x; yA[b] = v.y;
            float2 u = zcB[sw]; xB[b] = u.x; yB[b] = u.y;
        }
        dft16_quad(xA, yA, w1, w2, w3, b1, b2, b3);
        dft16_quad(xB, yB, w1, w2, w3, b1, b2, b3);
        #pragma unroll
        for (int c = 0; c < 4; ++c) {                   // X natural order
            int idx = q + 16*c + 64*r2;
            zcA[idx] = make_float2(xA[c], yA[c]);
            zcB[idx] = make_float2(xB[c], yB[c]);
        }
    }

    // ---- single-phase untangle + power, in place, both frames ----
    {
        float2* zcA = (float2*)zfA;
        float2* zcB = (float2*)zfB;
        const float2* we = (const float2*)g_wexp.v;
        float2 wk1 = we[lane], wk2 = we[64 + lane];
        const int m1 = (256 - lane) & 255;              // 0 or 193..255
        const int m2 = 192 - lane;                      // 129..192
        // ALL reads first (both frames), then writes (in-order DS per wave).
        // Bin 0 has weight 0 in the mel table -> unconditional pw[m1] write
        // (lane 0 overwrites pw[0] with |X[256]|^2, finite & unused).
        float2 Ak1 = zcA[lane], Am1 = zcA[m1], Ak2 = zcA[64 + lane], Am2 = zcA[m2];
        float2 A128 = zcA[128];
        float2 Bk1 = zcB[lane], Bm1 = zcB[m1], Bk2 = zcB[64 + lane], Bm2 = zcB[m2];
        float2 B128 = zcB[128];
        float pk, pm;
        pairpow(Ak1, Am1, wk1, pk, pm);
        zfA[lane] = pk; zfA[m1] = pm;
        pairpow(Ak2, Am2, wk2, pk, pm);
        zfA[64 + lane] = pk; zfA[m2] = pm;
        pairpow(Bk1, Bm1, wk1, pk, pm);
        zfB[lane] = pk; zfB[m1] = pm;
        pairpow(Bk2, Bm2, wk2, pk, pm);
        zfB[64 + lane] = pk; zfB[m2] = pm;
        if (lane == 0) {
            zfA[128] = fmaf(A128.x, A128.x, A128.y * A128.y);
            zfB[128] = fmaf(B128.x, B128.x, B128.y * B128.y);
        }
    }

    // ---- mel gather: tight windows (<=3 chunks, exec-masked), f32 weights ----
    {
        auto gather1 = [&](const float* pw, int j, int slot) {
            const int base = g_mel.base[j];
            const int nc   = g_mel.nc[j];
            float acc = 0.0f;
            #pragma unroll
            for (int c = 0; c < 3; ++c) {
                if (c == 0 || c < nc) {                 // masked lanes skip banks
                    float4 p0 = *(const float4*)&pw[base + 8 * c];
                    float4 p1 = *(const float4*)&pw[base + 8 * c + 4];
                    float4 wa = *(const float4*)&g_mel.w[c][j][0];
                    float4 wb = *(const float4*)&g_mel.w[c][j][4];
                    acc = fmaf(wa.x, p0.x, acc); acc = fmaf(wa.y, p0.y, acc);
                    acc = fmaf(wa.z, p0.z, acc); acc = fmaf(wa.w, p0.w, acc);
                    acc = fmaf(wb.x, p1.x, acc); acc = fmaf(wb.y, p1.y, acc);
                    acc = fmaf(wb.z, p1.z, acc); acc = fmaf(wb.w, p1.w, acc);
                }
            }
            res[slot][j] = __logf(fmaxf(acc, EPSV));    // linear in j: free
        };
        gather1(zfA, lane, wv);                         // mels 0..63, frame A
        gather1(zfB, lane, wv + 4);                     // mels 0..63, frame B
        if (lane < 32) {                                // mels 64..79, both
            int l2 = lane & 15, fb = lane >> 4;
            gather1(fb ? zfB : zfA, 64 + l2, fb ? wv + 4 : wv);
        }
    }
    __syncthreads();

    // ---- transposed output, 8B bursts (res reads linear in tid: free) ----
    const int nval = min(FPB, NFRM - f0);               // 8, or 6 in tail
    if (tid < NMELS) {
        size_t o = ((size_t)bb * NMELS + tid) * NFRM + (size_t)f0;
        *(float2*)&out[o]     = make_float2(res[0][tid], res[1][tid]);
        *(float2*)&out[o + 2] = make_float2(res[2][tid], res[3][tid]);
        *(float2*)&out[o + 4] = make_float2(res[4][tid], res[5][tid]);
        if (nval == 8)
            *(float2*)&out[o + 6] = make_float2(res[6][tid], res[7][tid]);
    }
}

extern "C" void kernel_launch(void* const* d_in, const int* in_sizes, int n_in,
                              void* d_out, int out_size, void* d_ws, size_t ws_size,
                              hipStream_t stream)
{
    const float* wav = (const float*)d_in[0];
    float* out = (float*)d_out;
    fbank_kernel<<<dim3(32 * BPB), dim3(256), 0, stream>>>(wav, out);
}